// Round 8
// baseline (81.701 us; speedup 1.0000x reference)
//
#include <hip/hip_runtime.h>
#include <hip/hip_bf16.h>
#include <stdint.h>

#define N_NODES 100000
#define DEG 16
#define IN_F 128
#define OUT_F 64
#define ALPHA 0.2f

typedef __attribute__((ext_vector_type(8))) short short8;
typedef __attribute__((ext_vector_type(4))) float f32x4;
typedef __attribute__((ext_vector_type(4))) int i32x4;
typedef __attribute__((ext_vector_type(4))) unsigned int u32x4;
typedef __attribute__((ext_vector_type(2))) unsigned int u32x2;

static __device__ __forceinline__ unsigned int pack2bf(float lo, float hi) {
    __hip_bfloat162 h = __float22bfloat162_rn(make_float2(lo, hi));
    unsigned int u; __builtin_memcpy(&u, &h, 4); return u;
}
static __device__ __forceinline__ unsigned short f2bf(float f) {
    __hip_bfloat16 h = __float2bfloat16(f);   // RTNE
    unsigned short u; __builtin_memcpy(&u, &h, 2); return u;
}

// Prep: w -> bf16 only.
__global__ __launch_bounds__(256) void prep_kernel(
    const float* __restrict__ w, unsigned short* __restrict__ wb)
{
    int idx = blockIdx.x * 256 + threadIdx.x;
    if (idx < OUT_F * IN_F) wb[idx] = f2bf(w[idx]);
}

// Kernel 1: byte-identical work to R7, run 3x internally (DIAGNOSIS ROUND).
// Idempotent: every rep recomputes and rewrites the same featb/a1 values.
__global__ __launch_bounds__(256) void gat_feat_kernel(
    const float* __restrict__ x, const unsigned short* __restrict__ wb,
    const float* __restrict__ a1w, const float* __restrict__ a1bp,
    unsigned short* __restrict__ featb, float* __restrict__ a1)
{
    __shared__ __align__(16) unsigned short lds[4][32][64];
    const int wid  = threadIdx.x >> 6;
    const int lane = threadIdx.x & 63;
    const int r = lane & 15;
    const int g = lane >> 4;
    const int base = (blockIdx.x * 4 + wid) * 32;
    if (base >= N_NODES) return;

    #pragma unroll 1
    for (int rep = 0; rep < 3; ++rep) {
        short8 bfrag[4][4];
        #pragma unroll
        for (int ft = 0; ft < 4; ++ft)
            #pragma unroll
            for (int ks = 0; ks < 4; ++ks)
                bfrag[ft][ks] = *(const short8*)(wb + (ft * 16 + r) * IN_F + ks * 32 + g * 8);

        f32x4 acc[2][4];
        #pragma unroll
        for (int mt = 0; mt < 2; ++mt)
            #pragma unroll
            for (int ft = 0; ft < 4; ++ft) acc[mt][ft] = (f32x4){0.f, 0.f, 0.f, 0.f};

        #pragma unroll
        for (int mt = 0; mt < 2; ++mt) {
            const float* xrow = x + (size_t)(base + mt * 16 + r) * IN_F;
            #pragma unroll
            for (int ks = 0; ks < 4; ++ks) {
                const float* xp = xrow + ks * 32 + g * 8;
                f32x4 x0 = *(const f32x4*)(xp);
                f32x4 x1 = *(const f32x4*)(xp + 4);
                u32x4 au;
                au[0] = pack2bf(x0[0], x0[1]);
                au[1] = pack2bf(x0[2], x0[3]);
                au[2] = pack2bf(x1[0], x1[1]);
                au[3] = pack2bf(x1[2], x1[3]);
                short8 af; __builtin_memcpy(&af, &au, 16);
                #pragma unroll
                for (int ft = 0; ft < 4; ++ft)
                    acc[mt][ft] = __builtin_amdgcn_mfma_f32_16x16x32_bf16(af, bfrag[ft][ks], acc[mt][ft], 0, 0, 0);
            }
        }

        float w1v[4];
        #pragma unroll
        for (int ft = 0; ft < 4; ++ft) w1v[ft] = a1w[ft * 16 + r];
        float p1[2][4] = {{0.f,0.f,0.f,0.f},{0.f,0.f,0.f,0.f}};
        #pragma unroll
        for (int mt = 0; mt < 2; ++mt)
            #pragma unroll
            for (int ft = 0; ft < 4; ++ft)
                #pragma unroll
                for (int reg = 0; reg < 4; ++reg)
                    p1[mt][reg] += acc[mt][ft][reg] * w1v[ft];
        #pragma unroll
        for (int m = 1; m <= 8; m <<= 1)
            #pragma unroll
            for (int mt = 0; mt < 2; ++mt)
                #pragma unroll
                for (int reg = 0; reg < 4; ++reg)
                    p1[mt][reg] += __shfl_xor(p1[mt][reg], m, 64);
        if (r == 0) {
            float b1 = a1bp[0];
            #pragma unroll
            for (int mt = 0; mt < 2; ++mt)
                #pragma unroll
                for (int reg = 0; reg < 4; ++reg)
                    a1[base + mt * 16 + g * 4 + reg] = p1[mt][reg] + b1;
        }

        #pragma unroll
        for (int mt = 0; mt < 2; ++mt)
            #pragma unroll
            for (int ft = 0; ft < 4; ++ft)
                #pragma unroll
                for (int reg = 0; reg < 4; ++reg)
                    lds[wid][mt * 16 + g * 4 + reg][ft * 16 + r] = f2bf(acc[mt][ft][reg]);
        const char* lsrc = (const char*)(&lds[wid][0][0]);
        char* gdst = (char*)featb + (size_t)base * (OUT_F * 2);
        #pragma unroll
        for (int t = 0; t < 4; ++t) {
            i32x4 v = *(const i32x4*)(lsrc + t * 1024 + lane * 16);
            *(i32x4*)(gdst + t * 1024 + lane * 16) = v;
        }
        asm volatile("" ::: "memory");   // no cross-rep CSE: reps do full work
    }
}

#define BFLO(w_) __uint_as_float((w_) << 16)
#define BFHI(w_) __uint_as_float((w_) & 0xffff0000u)

// Kernel 2: byte-identical work to R5/R7, run 2x internally (DIAGNOSIS ROUND).
__global__ __launch_bounds__(256) void gat_agg_kernel(
    const int* __restrict__ dst, const unsigned short* __restrict__ featb,
    const float* __restrict__ a1, const float* __restrict__ a2w,
    const float* __restrict__ a2bp, const float* __restrict__ bias,
    float* __restrict__ out)
{
    const int wid  = threadIdx.x >> 6;
    const int lane = threadIdx.x & 63;
    const int e0 = lane & 15;
    const int sb = lane & 48;
    const int i = (blockIdx.x * 4 + wid) * 4 + (lane >> 4);

    #pragma unroll 1
    for (int rep = 0; rep < 2; ++rep) {
        const int d = dst[i * DEG + e0];

#define GATH(t) \
        const int de##t = __shfl(d, sb + (t), 64); \
        const u32x2 u##t = *(const u32x2*)(featb + (unsigned)de##t * OUT_F + e0 * 4);
        GATH(0)  GATH(1)  GATH(2)  GATH(3)
        GATH(4)  GATH(5)  GATH(6)  GATH(7)
        GATH(8)  GATH(9)  GATH(10) GATH(11)
        GATH(12) GATH(13) GATH(14) GATH(15)
#undef GATH

        const float a1i = a1[i] + a2bp[0];
        const f32x4 aw = *(const f32x4*)(a2w + e0 * 4);
        const f32x4 bv = *(const f32x4*)(bias + e0 * 4);

        float acc0 = 0.f, acc1 = 0.f, acc2 = 0.f, acc3 = 0.f, ssum = 0.f;
#define EDGE(t) { \
        const float f0 = BFLO(u##t[0]), f1 = BFHI(u##t[0]); \
        const float f2 = BFLO(u##t[1]), f3 = BFHI(u##t[1]); \
        float p = f0 * aw[0] + f1 * aw[1] + f2 * aw[2] + f3 * aw[3]; \
        p += __shfl_xor(p, 1, 64); p += __shfl_xor(p, 2, 64); \
        p += __shfl_xor(p, 4, 64); p += __shfl_xor(p, 8, 64); \
        const float z = a1i + p; \
        const float s = __expf(fmaxf(z, ALPHA * z)); \
        ssum += s; \
        acc0 += s * f0; acc1 += s * f1; acc2 += s * f2; acc3 += s * f3; }
        EDGE(0)  EDGE(1)  EDGE(2)  EDGE(3)
        EDGE(4)  EDGE(5)  EDGE(6)  EDGE(7)
        EDGE(8)  EDGE(9)  EDGE(10) EDGE(11)
        EDGE(12) EDGE(13) EDGE(14) EDGE(15)
#undef EDGE

        const float inv = 1.0f / ssum;
        f32x4 o;
        o[0] = acc0 * inv + bv[0];
        o[1] = acc1 * inv + bv[1];
        o[2] = acc2 * inv + bv[2];
        o[3] = acc3 * inv + bv[3];
        __builtin_nontemporal_store(o, (f32x4*)(out + (unsigned)i * OUT_F + e0 * 4));
        asm volatile("" ::: "memory");   // no cross-rep CSE
    }
}

extern "C" void kernel_launch(void* const* d_in, const int* in_sizes, int n_in,
                              void* d_out, int out_size, void* d_ws, size_t ws_size,
                              hipStream_t stream) {
    (void)in_sizes; (void)n_in; (void)out_size; (void)ws_size;
    const float* x    = (const float*)d_in[0];
    const int*   edges= (const int*)d_in[1];
    const float* w    = (const float*)d_in[2];
    const float* a1w  = (const float*)d_in[3];
    const float* a1b  = (const float*)d_in[4];
    const float* a2w  = (const float*)d_in[5];
    const float* a2b  = (const float*)d_in[6];
    const float* bias = (const float*)d_in[7];
    float* out = (float*)d_out;

    unsigned short* featb = (unsigned short*)d_ws;
    float* a1 = (float*)((char*)d_ws + (size_t)N_NODES * OUT_F * 2);
    unsigned short* wb = (unsigned short*)(a1 + N_NODES);

    const int* dst = edges + (size_t)N_NODES * DEG;

    prep_kernel<<<dim3((OUT_F * IN_F + 255) / 256), dim3(256), 0, stream>>>(w, wb);
    gat_feat_kernel<<<dim3((N_NODES + 127) / 128), dim3(256), 0, stream>>>(
        x, wb, a1w, a1b, featb, a1);
    gat_agg_kernel<<<dim3(N_NODES / 16), dim3(256), 0, stream>>>(
        dst, featb, a1, a2w, a2b, bias, out);
}

// Round 9
// 58.033 us; speedup vs baseline: 1.4078x; 1.4078x over previous
//
#include <hip/hip_runtime.h>
#include <hip/hip_bf16.h>
#include <stdint.h>

#define N_NODES 100000
#define DEG 16
#define IN_F 128
#define OUT_F 64
#define ALPHA 0.2f

typedef __attribute__((ext_vector_type(8))) short short8;
typedef __attribute__((ext_vector_type(4))) float f32x4;
typedef __attribute__((ext_vector_type(4))) int i32x4;
typedef __attribute__((ext_vector_type(4))) unsigned int u32x4;
typedef __attribute__((ext_vector_type(2))) unsigned int u32x2;

static __device__ __forceinline__ unsigned int pack2bf(float lo, float hi) {
    __hip_bfloat162 h = __float22bfloat162_rn(make_float2(lo, hi));
    unsigned int u; __builtin_memcpy(&u, &h, 4); return u;
}
static __device__ __forceinline__ unsigned short f2bf(float f) {
    __hip_bfloat16 h = __float2bfloat16(f);   // RTNE
    unsigned short u; __builtin_memcpy(&u, &h, 2); return u;
}

// Prep: w -> bf16 only.
__global__ __launch_bounds__(256) void prep_kernel(
    const float* __restrict__ w, unsigned short* __restrict__ wb)
{
    int idx = blockIdx.x * 256 + threadIdx.x;
    if (idx < OUT_F * IN_F) wb[idx] = f2bf(w[idx]);
}

// Kernel 1: feat = x @ w^T via bf16 MFMA (f32 accum); a1 AND a2n from accumulators
// (a2n[i] = feat[i].a2w, so agg's per-edge score is a single L2-resident 4B gather
// instead of a 4-deep shfl reduction tree). R2-proven structure, ~5-7 us measured.
__global__ __launch_bounds__(256) void gat_feat_kernel(
    const float* __restrict__ x, const unsigned short* __restrict__ wb,
    const float* __restrict__ a1w, const float* __restrict__ a1bp,
    const float* __restrict__ a2w,
    unsigned short* __restrict__ featb, float* __restrict__ a1,
    float* __restrict__ a2n)
{
    __shared__ __align__(16) unsigned short lds[4][32][64]; // per-wave store-bounce tile
    const int wid  = threadIdx.x >> 6;
    const int lane = threadIdx.x & 63;
    const int r = lane & 15;   // A row / B col within 16-tile
    const int g = lane >> 4;   // k-group (8 contiguous k per group)
    const int base = (blockIdx.x * 4 + wid) * 32;
    if (base >= N_NODES) return;   // N % 32 == 0: active waves always full

    short8 bfrag[4][4];
    #pragma unroll
    for (int ft = 0; ft < 4; ++ft)
        #pragma unroll
        for (int ks = 0; ks < 4; ++ks)
            bfrag[ft][ks] = *(const short8*)(wb + (ft * 16 + r) * IN_F + ks * 32 + g * 8);

    f32x4 acc[2][4];
    #pragma unroll
    for (int mt = 0; mt < 2; ++mt)
        #pragma unroll
        for (int ft = 0; ft < 4; ++ft) acc[mt][ft] = (f32x4){0.f, 0.f, 0.f, 0.f};

    #pragma unroll
    for (int mt = 0; mt < 2; ++mt) {
        const float* xrow = x + (size_t)(base + mt * 16 + r) * IN_F;
        #pragma unroll
        for (int ks = 0; ks < 4; ++ks) {
            const float* xp = xrow + ks * 32 + g * 8;
            f32x4 x0 = *(const f32x4*)(xp);
            f32x4 x1 = *(const f32x4*)(xp + 4);
            u32x4 au;
            au[0] = pack2bf(x0[0], x0[1]);
            au[1] = pack2bf(x0[2], x0[3]);
            au[2] = pack2bf(x1[0], x1[1]);
            au[3] = pack2bf(x1[2], x1[3]);
            short8 af; __builtin_memcpy(&af, &au, 16);
            #pragma unroll
            for (int ft = 0; ft < 4; ++ft)
                acc[mt][ft] = __builtin_amdgcn_mfma_f32_16x16x32_bf16(af, bfrag[ft][ks], acc[mt][ft], 0, 0, 0);
        }
    }
    // C/D layout (HW-verified): col = lane&15 -> feature ft*16+r; row = g*4+reg -> node mt*16+g*4+reg

    // a1 = feat@a1w + b1 and a2n = feat@a2w (unbiased) from the f32 accumulators
    float w1v[4], w2v[4];
    #pragma unroll
    for (int ft = 0; ft < 4; ++ft) { w1v[ft] = a1w[ft * 16 + r]; w2v[ft] = a2w[ft * 16 + r]; }
    float p1[2][4] = {{0.f,0.f,0.f,0.f},{0.f,0.f,0.f,0.f}};
    float p2[2][4] = {{0.f,0.f,0.f,0.f},{0.f,0.f,0.f,0.f}};
    #pragma unroll
    for (int mt = 0; mt < 2; ++mt)
        #pragma unroll
        for (int ft = 0; ft < 4; ++ft)
            #pragma unroll
            for (int reg = 0; reg < 4; ++reg) {
                p1[mt][reg] += acc[mt][ft][reg] * w1v[ft];
                p2[mt][reg] += acc[mt][ft][reg] * w2v[ft];
            }
    #pragma unroll
    for (int m = 1; m <= 8; m <<= 1)
        #pragma unroll
        for (int mt = 0; mt < 2; ++mt)
            #pragma unroll
            for (int reg = 0; reg < 4; ++reg) {
                p1[mt][reg] += __shfl_xor(p1[mt][reg], m, 64);
                p2[mt][reg] += __shfl_xor(p2[mt][reg], m, 64);
            }
    if (r == 0) {
        float b1 = a1bp[0];
        #pragma unroll
        for (int mt = 0; mt < 2; ++mt)
            #pragma unroll
            for (int reg = 0; reg < 4; ++reg) {
                a1[base + mt * 16 + g * 4 + reg]  = p1[mt][reg] + b1;
                a2n[base + mt * 16 + g * 4 + reg] = p2[mt][reg];
            }
    }

    // feat -> bf16, bounce through LDS so the global store is fully coalesced
    #pragma unroll
    for (int mt = 0; mt < 2; ++mt)
        #pragma unroll
        for (int ft = 0; ft < 4; ++ft)
            #pragma unroll
            for (int reg = 0; reg < 4; ++reg)
                lds[wid][mt * 16 + g * 4 + reg][ft * 16 + r] = f2bf(acc[mt][ft][reg]);
    const char* lsrc = (const char*)(&lds[wid][0][0]);
    char* gdst = (char*)featb + (size_t)base * (OUT_F * 2);
    #pragma unroll
    for (int t = 0; t < 4; ++t) {
        i32x4 v = *(const i32x4*)(lsrc + t * 1024 + lane * 16);
        *(i32x4*)(gdst + t * 1024 + lane * 16) = v;
    }
}

#define BFLO(w_) __uint_as_float((w_) << 16)
#define BFHI(w_) __uint_as_float((w_) & 0xffff0000u)

// Kernel 2: per-node scores + gather-aggregate. One wave = 4 nodes x 16 lanes.
// Lane e0 owns edge e0's score (ONE exp/lane, score = a1[i] + a2n[d], a2n is a
// 400 KB L2-resident array -> cheap 4B gather) and feature-chunk e0 for the row
// gathers. No per-edge shfl reduction trees (the R5-R8 latency chain); just one
// 4-step ssum reduce + 16 score broadcasts. All 16 row-gathers are named registers
// issued before any dependent compute.
__global__ __launch_bounds__(256) void gat_agg_kernel(
    const int* __restrict__ dst, const unsigned short* __restrict__ featb,
    const float* __restrict__ a1, const float* __restrict__ a2n,
    const float* __restrict__ a2bp, const float* __restrict__ bias,
    float* __restrict__ out)
{
    const int wid  = threadIdx.x >> 6;
    const int lane = threadIdx.x & 63;
    const int e0 = lane & 15;
    const int sb = lane & 48;
    const int i = (blockIdx.x * 4 + wid) * 4 + (lane >> 4);   // N % 16 == 0: exact

    const int d = dst[i * DEG + e0];

    // fire all 16 row-gathers (chunk e0 of edge t's row) up front
#define GATH(t) \
    const int de##t = __shfl(d, sb + (t), 64); \
    const u32x2 u##t = *(const u32x2*)(featb + (unsigned)de##t * OUT_F + e0 * 4);
    GATH(0)  GATH(1)  GATH(2)  GATH(3)
    GATH(4)  GATH(5)  GATH(6)  GATH(7)
    GATH(8)  GATH(9)  GATH(10) GATH(11)
    GATH(12) GATH(13) GATH(14) GATH(15)
#undef GATH

    // own-edge score while the row-gathers are in flight
    const float z = (a1[i] + a2bp[0]) + a2n[d];     // a1 includes a1 bias
    const float s = __expf(fmaxf(z, ALPHA * z));    // leaky_relu == max(z, 0.2z)
    float ssum = s;
    ssum += __shfl_xor(ssum, 1, 64);
    ssum += __shfl_xor(ssum, 2, 64);
    ssum += __shfl_xor(ssum, 4, 64);
    ssum += __shfl_xor(ssum, 8, 64);

    const f32x4 bv = *(const f32x4*)(bias + e0 * 4);

    float acc0 = 0.f, acc1 = 0.f, acc2 = 0.f, acc3 = 0.f;
#define EDGE(t) { \
    const float se = __shfl(s, sb + (t), 64); \
    acc0 += se * BFLO(u##t[0]); acc1 += se * BFHI(u##t[0]); \
    acc2 += se * BFLO(u##t[1]); acc3 += se * BFHI(u##t[1]); }
    EDGE(0)  EDGE(1)  EDGE(2)  EDGE(3)
    EDGE(4)  EDGE(5)  EDGE(6)  EDGE(7)
    EDGE(8)  EDGE(9)  EDGE(10) EDGE(11)
    EDGE(12) EDGE(13) EDGE(14) EDGE(15)
#undef EDGE

    const float inv = 1.0f / ssum;
    f32x4 o;
    o[0] = acc0 * inv + bv[0];
    o[1] = acc1 * inv + bv[1];
    o[2] = acc2 * inv + bv[2];
    o[3] = acc3 * inv + bv[3];
    __builtin_nontemporal_store(o, (f32x4*)(out + (unsigned)i * OUT_F + e0 * 4));
}

extern "C" void kernel_launch(void* const* d_in, const int* in_sizes, int n_in,
                              void* d_out, int out_size, void* d_ws, size_t ws_size,
                              hipStream_t stream) {
    (void)in_sizes; (void)n_in; (void)out_size; (void)ws_size;
    const float* x    = (const float*)d_in[0];
    const int*   edges= (const int*)d_in[1];   // [2, E] int32, row0=src, row1=dst
    const float* w    = (const float*)d_in[2];
    const float* a1w  = (const float*)d_in[3];
    const float* a1b  = (const float*)d_in[4];
    const float* a2w  = (const float*)d_in[5];
    const float* a2b  = (const float*)d_in[6];
    const float* bias = (const float*)d_in[7];
    float* out = (float*)d_out;

    // ws layout (16B-aligned): featb | a1 | a2n | wb
    unsigned short* featb = (unsigned short*)d_ws;                       // N*64 bf16 = 12.8 MB
    float* a1  = (float*)((char*)d_ws + (size_t)N_NODES * OUT_F * 2);
    float* a2n = a1 + N_NODES;
    unsigned short* wb = (unsigned short*)(a2n + N_NODES);

    const int* dst = edges + (size_t)N_NODES * DEG; // edges[1]

    prep_kernel<<<dim3((OUT_F * IN_F + 255) / 256), dim3(256), 0, stream>>>(w, wb);
    gat_feat_kernel<<<dim3((N_NODES + 127) / 128), dim3(256), 0, stream>>>(
        x, wb, a1w, a1b, a2w, featb, a1, a2n);
    gat_agg_kernel<<<dim3(N_NODES / 16), dim3(256), 0, stream>>>(
        dst, featb, a1, a2n, a2b, bias, out);
}